// Round 3
// baseline (368.857 us; speedup 1.0000x reference)
//
#include <hip/hip_runtime.h>

#define NN 30000
#define NE 120000
#define NG 256
#define FIN 16
#define HD 32
#define TOUT 10
#define EPSV 1e-5f
#define NB_SCAN 30   // ceil(NN/1024)

__device__ __forceinline__ void atomAddF(float* p, float v) {
    unsafeAtomicAdd(p, v);  // global_atomic_add_f32
}

// ---------------------------------------------------------------------------
// Fused: per-edge in-degree count (atomics) + per-graph node count
// (sorted-batch run-length compress, one atomic per run per wave).
// ---------------------------------------------------------------------------
__global__ __launch_bounds__(256) void count_deg_kernel(
    const int* __restrict__ eidx, const int* __restrict__ batch,
    int* __restrict__ deg_in, float* __restrict__ deg_g)
{
    const int t = blockIdx.x * 256 + threadIdx.x;
    if (t < NE) atomicAdd(&deg_in[eidx[NE + t]], 1);

    const int lane = threadIdx.x & 63;
    const int g = (t < NN) ? batch[t] : -1;
    const int prev = __shfl_up(g, 1);
    const bool head = (lane == 0) || (g != prev);
    const unsigned long long heads = __ballot(head);
    if (head && g >= 0) {
        unsigned long long higher = (lane < 63) ? (heads >> (lane + 1)) : 0ULL;
        int next = higher ? (lane + __ffsll(higher)) : 64;
        atomAddF(&deg_g[g], (float)(next - lane));
    }
}

// ---------------------------------------------------------------------------
// 3-phase exclusive scan of deg_in -> row_start / cursor
// ---------------------------------------------------------------------------
__global__ __launch_bounds__(1024) void scan_phase1(
    const int* __restrict__ deg_in, int* __restrict__ row_start,
    int* __restrict__ blocksum)
{
    __shared__ int wsum[16];
    const int t = threadIdx.x, lane = t & 63, w = t >> 6;
    const int idx = blockIdx.x * 1024 + t;
    const int v = (idx < NN) ? deg_in[idx] : 0;
    int s = v;
    #pragma unroll
    for (int off = 1; off < 64; off <<= 1) {
        int u = __shfl_up(s, off, 64);
        if (lane >= off) s += u;
    }
    if (lane == 63) wsum[w] = s;
    __syncthreads();
    if (w == 0) {
        int ws = (lane < 16) ? wsum[lane] : 0;
        #pragma unroll
        for (int off = 1; off < 16; off <<= 1) {
            int u = __shfl_up(ws, off, 64);
            if (lane >= off) ws += u;
        }
        if (lane < 16) wsum[lane] = ws;
    }
    __syncthreads();
    const int incl = s + ((w > 0) ? wsum[w - 1] : 0);
    if (idx < NN) row_start[idx] = incl - v;  // block-local exclusive
    if (t == 1023) blocksum[blockIdx.x] = incl;
}

__global__ __launch_bounds__(64) void scan_phase2(
    const int* __restrict__ blocksum, int* __restrict__ blockoff)
{
    const int t = threadIdx.x;
    const int v = (t < NB_SCAN) ? blocksum[t] : 0;
    int s = v;
    #pragma unroll
    for (int off = 1; off < 64; off <<= 1) {
        int u = __shfl_up(s, off, 64);
        if (t >= off) s += u;
    }
    if (t < NB_SCAN) blockoff[t] = s - v;
}

__global__ __launch_bounds__(1024) void scan_phase3(
    const int* __restrict__ blockoff, int* __restrict__ row_start,
    int* __restrict__ cursor)
{
    const int idx = blockIdx.x * 1024 + threadIdx.x;
    if (idx < NN) {
        const int r = row_start[idx] + blockoff[blockIdx.x];
        row_start[idx] = r;
        cursor[idx]    = r;
    }
    if (blockIdx.x == 0 && threadIdx.x == 0) row_start[NN] = NE;
}

__global__ __launch_bounds__(256) void csr_scatter(
    const int* __restrict__ eidx, int* __restrict__ cursor,
    int2* __restrict__ csr)
{
    const int e = blockIdx.x * 256 + threadIdx.x;
    if (e < NE) {
        const int d = eidx[NE + e];
        const int slot = atomicAdd(&cursor[d], 1);
        csr[slot] = make_int2(e, eidx[e]);  // (edge id, src id)
    }
}

// ---------------------------------------------------------------------------
// Fused per-node layer, ONE NODE PER WAVE (4 waves / 256-block, no barriers).
// Phase A: lane groups of IN lanes process edges in parallel (64/IN-way),
//          t[f][i] partials reduced across groups via shfl_xor.
// T round-trips through wave-private LDS (DS ops are in-order per wave;
// wave_barrier pins compiler ordering). Phase B: lane=o, f-range split
// across wave halves, shfl_xor(32) combines. Epilogue gsn+BN+ReLU or pool.
// ---------------------------------------------------------------------------
template<int IN, bool FINAL>
__global__ __launch_bounds__(256) void fused_layer(
    const float* __restrict__ hin,       // [NN, IN]
    const float* __restrict__ ea,        // [NE, 8]
    const int2*  __restrict__ csr,       // [NE] (e, s) grouped by dst
    const int*   __restrict__ row_start, // [NN+1]
    const float* __restrict__ nn_w,      // [8, IN*32]  ([f][i][o])
    const float* __restrict__ nn_b,      // [IN*32]
    const float* __restrict__ root,      // [IN*32]
    const float* __restrict__ bias,      // [32]
    const int*   __restrict__ batch,
    const float* __restrict__ deg_g,     // [NG]
    const float* __restrict__ bn_g,
    const float* __restrict__ bn_b,
    const float* __restrict__ bn_m,
    const float* __restrict__ bn_v,
    float*       __restrict__ out)       // [NN,32] or pooled [NG,32]
{
    constexpr int NQ = 64 / IN;          // edge-parallel groups
    __shared__ float Ts[4][10][IN];
    const int tid = threadIdx.x;
    const int wv  = tid >> 6;            // wave in block
    const int l   = tid & 63;
    const int d   = blockIdx.x * 4 + wv; // NN%4==0: always valid
    const int i   = l & (IN - 1);
    const int q   = l / IN;              // edge group

    float t[9];
    #pragma unroll
    for (int f = 0; f < 9; ++f) t[f] = 0.0f;

    const int p0 = row_start[d];
    const int p1 = row_start[d + 1];

    int p = p0 + q;
    int2 es = (p < p1) ? csr[p] : make_int2(0, 0);
    while (p < p1) {
        const int pn = p + NQ;
        const int2 esn = (pn < p1) ? csr[pn] : es;   // prefetch next
        const float xv = hin[(long)es.y * IN + i];
        const float4 a = *(const float4*)(ea + (long)es.x * 8);
        const float4 b = *(const float4*)(ea + (long)es.x * 8 + 4);
        t[0] = fmaf(a.x, xv, t[0]);
        t[1] = fmaf(a.y, xv, t[1]);
        t[2] = fmaf(a.z, xv, t[2]);
        t[3] = fmaf(a.w, xv, t[3]);
        t[4] = fmaf(b.x, xv, t[4]);
        t[5] = fmaf(b.y, xv, t[5]);
        t[6] = fmaf(b.z, xv, t[6]);
        t[7] = fmaf(b.w, xv, t[7]);
        t[8] += xv;
        es = esn; p = pn;
    }

    // reduce partials across edge groups
    #pragma unroll
    for (int f = 0; f < 9; ++f) {
        if (IN == 16) t[f] += __shfl_xor(t[f], 16, 64);
        t[f] += __shfl_xor(t[f], 32, 64);
    }

    // write T to wave-private LDS (lanes < IN), plus own row for root term
    if (l < IN) {
        #pragma unroll
        for (int f = 0; f < 9; ++f) Ts[wv][f][i] = t[f];
        Ts[wv][9][i] = hin[(long)d * IN + i];
    }
    __builtin_amdgcn_wave_barrier();   // DS ops are in-order per wave

    // Phase B: lane = o, halves split the 10 f-rows 5/5
    const int o = l & 31;
    const int h = l >> 5;
    float acc = (h == 0) ? bias[o] : 0.0f;

    #define FMA_ROW(Frow, WP)                                            \
        {                                                                \
            const float* __restrict__ wp = (WP);                         \
            _Pragma("unroll")                                            \
            for (int i4 = 0; i4 < IN / 4; ++i4) {                        \
                const float4 tv = *(const float4*)(&Ts[wv][Frow][4*i4]); \
                const float* w4 = wp + i4 * 128 + o;                     \
                acc = fmaf(tv.x, w4[0],  acc);                           \
                acc = fmaf(tv.y, w4[32], acc);                           \
                acc = fmaf(tv.z, w4[64], acc);                           \
                acc = fmaf(tv.w, w4[96], acc);                           \
            }                                                            \
        }

    if (h == 0) {
        FMA_ROW(0, nn_w + 0 * (IN * 32));
        FMA_ROW(1, nn_w + 1 * (IN * 32));
        FMA_ROW(2, nn_w + 2 * (IN * 32));
        FMA_ROW(3, nn_w + 3 * (IN * 32));
        FMA_ROW(4, nn_w + 4 * (IN * 32));
    } else {
        FMA_ROW(5, nn_w + 5 * (IN * 32));
        FMA_ROW(6, nn_w + 6 * (IN * 32));
        FMA_ROW(7, nn_w + 7 * (IN * 32));
        FMA_ROW(8, nn_b);
        FMA_ROW(9, root);
    }
    #undef FMA_ROW

    acc += __shfl_xor(acc, 32, 64);
    if (h != 0) return;

    const int g = batch[d];
    if (!FINAL) {
        float dg = deg_g[g];
        dg = dg > 0.0f ? dg : 1.0f;
        float v = acc * (1.0f / sqrtf(dg));
        const float s = bn_g[o] / sqrtf(bn_v[o] + EPSV);
        v = (v - bn_m[o]) * s + bn_b[o];
        out[(long)d * 32 + o] = v > 0.0f ? v : 0.0f;
    } else {
        atomAddF(&out[g * 32 + o], acc);
    }
}

// ---------------------------------------------------------------------------
// Head: pooled/cnt -> relu(@w1+b1) @ w2 + b2. One thread per graph.
// ---------------------------------------------------------------------------
__global__ __launch_bounds__(64) void head_kernel(
    const float* __restrict__ pooled,
    const float* __restrict__ deg,
    const float* __restrict__ w1,
    const float* __restrict__ b1,
    const float* __restrict__ w2,
    const float* __restrict__ b2,
    float*       __restrict__ out)
{
    const int g = blockIdx.x * 64 + threadIdx.x;
    if (g >= NG) return;
    float cnt = deg[g];
    cnt = cnt > 1.0f ? cnt : 1.0f;

    float p[HD];
    #pragma unroll
    for (int i = 0; i < HD; ++i) p[i] = pooled[g * HD + i] / cnt;

    float hid[HD];
    #pragma unroll
    for (int j = 0; j < HD; ++j) {
        float a = b1[j];
        #pragma unroll
        for (int i = 0; i < HD; ++i)
            a = fmaf(p[i], w1[i * HD + j], a);
        hid[j] = a > 0.0f ? a : 0.0f;
    }
    #pragma unroll
    for (int t = 0; t < TOUT; ++t) {
        float a = b2[t];
        #pragma unroll
        for (int j = 0; j < HD; ++j)
            a = fmaf(hid[j], w2[j * TOUT + t], a);
        out[g * TOUT + t] = a;
    }
}

// ---------------------------------------------------------------------------
extern "C" void kernel_launch(void* const* d_in, const int* in_sizes, int n_in,
                              void* d_out, int out_size, void* d_ws, size_t ws_size,
                              hipStream_t stream)
{
    const float* x        = (const float*)d_in[0];
    const float* ea       = (const float*)d_in[1];
    const int*   eidx     = (const int*)  d_in[2];
    const int*   batch    = (const int*)  d_in[3];
    const float* c1_nn_w  = (const float*)d_in[4];
    const float* c1_nn_b  = (const float*)d_in[5];
    const float* c1_root  = (const float*)d_in[6];
    const float* c1_bias  = (const float*)d_in[7];
    const float* c2_nn_w  = (const float*)d_in[8];
    const float* c2_nn_b  = (const float*)d_in[9];
    const float* c2_root  = (const float*)d_in[10];
    const float* c2_bias  = (const float*)d_in[11];
    const float* c3_nn_w  = (const float*)d_in[12];
    const float* c3_nn_b  = (const float*)d_in[13];
    const float* c3_root  = (const float*)d_in[14];
    const float* c3_bias  = (const float*)d_in[15];
    const float* bn1_g    = (const float*)d_in[16];
    const float* bn1_b    = (const float*)d_in[17];
    const float* bn1_m    = (const float*)d_in[18];
    const float* bn1_v    = (const float*)d_in[19];
    const float* bn2_g    = (const float*)d_in[20];
    const float* bn2_b    = (const float*)d_in[21];
    const float* bn2_m    = (const float*)d_in[22];
    const float* bn2_v    = (const float*)d_in[23];
    const float* mlp_w1   = (const float*)d_in[24];
    const float* mlp_b1   = (const float*)d_in[25];
    const float* mlp_w2   = (const float*)d_in[26];
    const float* mlp_b2   = (const float*)d_in[27];
    float* out = (float*)d_out;

    // workspace layout (deg_g and pooled adjacent -> single memset)
    float* h1     = (float*)d_ws;            // NN*32
    float* h2     = h1 + NN * HD;            // NN*32
    float* deg_g  = h2 + NN * HD;            // NG
    float* pooled = deg_g + NG;              // NG*32
    int*   ibase  = (int*)(pooled + NG * HD);
    int2*  csr    = (int2*)ibase;            // NE int2
    int*   deg_in = ibase + 2 * NE;          // NN
    int*   row_s  = deg_in + NN;             // NN+1
    int*   cursor = row_s + NN + 1;          // NN
    int*   bsum   = cursor + NN;             // NB_SCAN
    int*   boff   = bsum + NB_SCAN;          // NB_SCAN

    hipMemsetAsync(deg_in, 0, sizeof(int) * NN, stream);
    hipMemsetAsync(deg_g,  0, sizeof(float) * (NG + NG * HD), stream);

    const int egrid = (NE + 255) / 256;

    count_deg_kernel<<<egrid, 256, 0, stream>>>(eidx, batch, deg_in, deg_g);
    scan_phase1<<<NB_SCAN, 1024, 0, stream>>>(deg_in, row_s, bsum);
    scan_phase2<<<1, 64, 0, stream>>>(bsum, boff);
    scan_phase3<<<NB_SCAN, 1024, 0, stream>>>(boff, row_s, cursor);
    csr_scatter<<<egrid, 256, 0, stream>>>(eidx, cursor, csr);

    const int lgrid = NN / 4;  // 7500, one node per wave

    fused_layer<FIN, false><<<lgrid, 256, 0, stream>>>(
        x, ea, csr, row_s, c1_nn_w, c1_nn_b, c1_root, c1_bias,
        batch, deg_g, bn1_g, bn1_b, bn1_m, bn1_v, h1);

    fused_layer<HD, false><<<lgrid, 256, 0, stream>>>(
        h1, ea, csr, row_s, c2_nn_w, c2_nn_b, c2_root, c2_bias,
        batch, deg_g, bn2_g, bn2_b, bn2_m, bn2_v, h2);

    fused_layer<HD, true><<<lgrid, 256, 0, stream>>>(
        h2, ea, csr, row_s, c3_nn_w, c3_nn_b, c3_root, c3_bias,
        batch, deg_g, nullptr, nullptr, nullptr, nullptr, pooled);

    head_kernel<<<(NG + 63) / 64, 64, 0, stream>>>(pooled, deg_g, mlp_w1, mlp_b1,
                                                   mlp_w2, mlp_b2, out);
}

// Round 4
// 266.422 us; speedup vs baseline: 1.3845x; 1.3845x over previous
//
#include <hip/hip_runtime.h>

#define NN 30000
#define NE 120000
#define NG 256
#define FIN 16
#define HD 32
#define TOUT 10
#define EPSV 1e-5f
#define NB_SCAN 30   // ceil(NN/1024)

__device__ __forceinline__ void atomAddF(float* p, float v) {
    unsafeAtomicAdd(p, v);  // global_atomic_add_f32
}

// ---------------------------------------------------------------------------
// Fused: per-edge in-degree count + per-graph node count (run-length).
// ---------------------------------------------------------------------------
__global__ __launch_bounds__(256) void count_deg_kernel(
    const int* __restrict__ eidx, const int* __restrict__ batch,
    int* __restrict__ deg_in, float* __restrict__ deg_g)
{
    const int t = blockIdx.x * 256 + threadIdx.x;
    if (t < NE) atomicAdd(&deg_in[eidx[NE + t]], 1);

    const int lane = threadIdx.x & 63;
    const int g = (t < NN) ? batch[t] : -1;
    const int prev = __shfl_up(g, 1);
    const bool head = (lane == 0) || (g != prev);
    const unsigned long long heads = __ballot(head);
    if (head && g >= 0) {
        unsigned long long higher = (lane < 63) ? (heads >> (lane + 1)) : 0ULL;
        int next = higher ? (lane + __ffsll(higher)) : 64;
        atomAddF(&deg_g[g], (float)(next - lane));
    }
}

// ---------------------------------------------------------------------------
// 3-phase exclusive scan of deg_in -> row_start / cursor
// ---------------------------------------------------------------------------
__global__ __launch_bounds__(1024) void scan_phase1(
    const int* __restrict__ deg_in, int* __restrict__ row_start,
    int* __restrict__ blocksum)
{
    __shared__ int wsum[16];
    const int t = threadIdx.x, lane = t & 63, w = t >> 6;
    const int idx = blockIdx.x * 1024 + t;
    const int v = (idx < NN) ? deg_in[idx] : 0;
    int s = v;
    #pragma unroll
    for (int off = 1; off < 64; off <<= 1) {
        int u = __shfl_up(s, off, 64);
        if (lane >= off) s += u;
    }
    if (lane == 63) wsum[w] = s;
    __syncthreads();
    if (w == 0) {
        int ws = (lane < 16) ? wsum[lane] : 0;
        #pragma unroll
        for (int off = 1; off < 16; off <<= 1) {
            int u = __shfl_up(ws, off, 64);
            if (lane >= off) ws += u;
        }
        if (lane < 16) wsum[lane] = ws;
    }
    __syncthreads();
    const int incl = s + ((w > 0) ? wsum[w - 1] : 0);
    if (idx < NN) row_start[idx] = incl - v;  // block-local exclusive
    if (t == 1023) blocksum[blockIdx.x] = incl;
}

__global__ __launch_bounds__(64) void scan_phase2(
    const int* __restrict__ blocksum, int* __restrict__ blockoff)
{
    const int t = threadIdx.x;
    const int v = (t < NB_SCAN) ? blocksum[t] : 0;
    int s = v;
    #pragma unroll
    for (int off = 1; off < 64; off <<= 1) {
        int u = __shfl_up(s, off, 64);
        if (t >= off) s += u;
    }
    if (t < NB_SCAN) blockoff[t] = s - v;
}

__global__ __launch_bounds__(1024) void scan_phase3(
    const int* __restrict__ blockoff, int* __restrict__ row_start,
    int* __restrict__ cursor)
{
    const int idx = blockIdx.x * 1024 + threadIdx.x;
    if (idx < NN) {
        const int r = row_start[idx] + blockoff[blockIdx.x];
        row_start[idx] = r;
        cursor[idx]    = r;
    }
    if (blockIdx.x == 0 && threadIdx.x == 0) row_start[NN] = NE;
}

__global__ __launch_bounds__(256) void csr_scatter(
    const int* __restrict__ eidx, int* __restrict__ cursor,
    int2* __restrict__ csr)
{
    const int e = blockIdx.x * 256 + threadIdx.x;
    if (e < NE) {
        const int d = eidx[NE + e];
        const int slot = atomicAdd(&cursor[d], 1);
        csr[slot] = make_int2(e, eidx[e]);  // (edge id, src id)
    }
}

// ---------------------------------------------------------------------------
// Fused per-node layer. 2 nodes per wave (32 lanes/node, ALL lanes active —
// no divergent half-split). 16 nodes per block; weights staged once in LDS
// in quad-interleaved layout [row][i/4][o][i%4] so phase B uses ds_read_b128
// (4 weights / instr). T exchange is wave-private (wave_barrier only).
// Phase A: IN=16 uses 2 edge subgroups per node (shfl_xor(16) reduce);
// depth-1 software pipeline on csr/x/ea loads.
// ---------------------------------------------------------------------------
template<int IN, bool FINAL>
__global__ __launch_bounds__(256) void fused_layer(
    const float* __restrict__ hin,       // [NN, IN]
    const float* __restrict__ ea,        // [NE, 8]
    const int2*  __restrict__ csr,       // [NE] (e, s) grouped by dst
    const int*   __restrict__ row_start, // [NN+1]
    const float* __restrict__ nn_w,      // [8, IN*32]
    const float* __restrict__ nn_b,      // [IN*32]
    const float* __restrict__ root,      // [IN*32]
    const float* __restrict__ bias,      // [32]
    const int*   __restrict__ batch,
    const float* __restrict__ deg_g,     // [NG]
    const float* __restrict__ bn_g,
    const float* __restrict__ bn_b,
    const float* __restrict__ bn_m,
    const float* __restrict__ bn_v,
    float*       __restrict__ out)       // [NN,32] or pooled [NG,32]
{
    constexpr int WTOT = 10 * IN * 32;   // staged weight floats
    constexpr int NQ2  = 32 / IN;        // edge subgroups per node
    __shared__ float Wl[WTOT];
    __shared__ float Ts[4][2][10][IN];

    const int tid = threadIdx.x;
    const int wv  = tid >> 6;            // wave in block
    const int l   = tid & 63;
    const int l5  = l & 31;              // lane within node group
    const int pr  = l >> 5;              // which node of the wave's pair
    const int i   = l5 & (IN - 1);
    const int q   = l5 / IN;             // edge subgroup (0 for IN=32)
    const int o   = l5;                  // output channel in phase B

    // ---- stage weights: dst[row][i4][o][il] = src[row][i][o] ----
    for (int idx = tid; idx < WTOT; idx += 256) {
        const int row = idx / (IN * 32);
        const int r   = idx % (IN * 32);
        const int i4  = r >> 7;
        const int rr  = r & 127;
        const int oo  = rr >> 2;
        const int il  = rr & 3;
        const int ii  = i4 * 4 + il;
        const float* src = (row < 8) ? (nn_w + row * (IN * 32))
                                     : (row == 8 ? nn_b : root);
        Wl[idx] = src[ii * 32 + oo];
    }
    __syncthreads();

    #pragma unroll
    for (int j = 0; j < 2; ++j) {        // 16 nodes/block = 2 per wave-slot
        const int d = blockIdx.x * 16 + j * 8 + wv * 2 + pr;  // < NN always

        // ---------------- phase A: gather + per-edge rank-1 ----------------
        float t[9];
        #pragma unroll
        for (int f = 0; f < 9; ++f) t[f] = 0.0f;

        const int p0 = row_start[d];
        const int p1 = row_start[d + 1];

        int p = p0 + q;
        int2 es = (p < p1) ? csr[p] : make_int2(0, 0);
        float  xv = hin[(long)es.y * IN + i];
        float4 a  = *(const float4*)(ea + (long)es.x * 8);
        float4 b  = *(const float4*)(ea + (long)es.x * 8 + 4);

        while (p < p1) {
            const int pn = p + NQ2;
            const int2 esn = (pn < p1) ? csr[pn] : make_int2(0, 0);
            const float  xvn = hin[(long)esn.y * IN + i];
            const float4 an  = *(const float4*)(ea + (long)esn.x * 8);
            const float4 bn  = *(const float4*)(ea + (long)esn.x * 8 + 4);

            t[0] = fmaf(a.x, xv, t[0]);
            t[1] = fmaf(a.y, xv, t[1]);
            t[2] = fmaf(a.z, xv, t[2]);
            t[3] = fmaf(a.w, xv, t[3]);
            t[4] = fmaf(b.x, xv, t[4]);
            t[5] = fmaf(b.y, xv, t[5]);
            t[6] = fmaf(b.z, xv, t[6]);
            t[7] = fmaf(b.w, xv, t[7]);
            t[8] += xv;

            p = pn; es = esn; xv = xvn; a = an; b = bn;
        }

        if (IN == 16) {                  // reduce across the 2 edge subgroups
            #pragma unroll
            for (int f = 0; f < 9; ++f) t[f] += __shfl_xor(t[f], 16, 64);
        }

        __builtin_amdgcn_wave_barrier(); // anti-dep vs prev iter's T reads
        if (l5 < IN) {
            #pragma unroll
            for (int f = 0; f < 9; ++f) Ts[wv][pr][f][i] = t[f];
            Ts[wv][pr][9][i] = hin[(long)d * IN + i];   // own row (root term)
        }
        __builtin_amdgcn_wave_barrier(); // DS ops in-order per wave

        // ---------------- phase B: acc[o] = sum_k W[k][o] * T[k] -----------
        float acc = bias[o];
        #pragma unroll
        for (int row = 0; row < 10; ++row) {
            const float* wrow = Wl + row * (IN * 32);
            #pragma unroll
            for (int i4 = 0; i4 < IN / 4; ++i4) {
                const float4 w4 = *(const float4*)(wrow + i4 * 128 + (o << 2));
                const float4 tv = *(const float4*)(&Ts[wv][pr][row][i4 << 2]);
                acc = fmaf(tv.x, w4.x, acc);
                acc = fmaf(tv.y, w4.y, acc);
                acc = fmaf(tv.z, w4.z, acc);
                acc = fmaf(tv.w, w4.w, acc);
            }
        }

        // ---------------- epilogue ----------------
        const int g = batch[d];
        if (!FINAL) {
            float dg = deg_g[g];
            dg = dg > 0.0f ? dg : 1.0f;
            float v = acc * (1.0f / sqrtf(dg));
            const float s = bn_g[o] / sqrtf(bn_v[o] + EPSV);
            v = (v - bn_m[o]) * s + bn_b[o];
            out[(long)d * 32 + o] = v > 0.0f ? v : 0.0f;
        } else {
            float v = acc;
            const int   g2 = __shfl(g, l ^ 32, 64);
            const float v2 = __shfl(v, l ^ 32, 64);
            bool do_store = true;
            if (g2 == g) {                 // merge wave's node pair
                if (l & 32) do_store = false;
                else        v += v2;
            }
            if (do_store) atomAddF(&out[g * 32 + o], v);
        }
    }
}

// ---------------------------------------------------------------------------
// Head: pooled/cnt -> relu(@w1+b1) @ w2 + b2. One thread per graph.
// ---------------------------------------------------------------------------
__global__ __launch_bounds__(64) void head_kernel(
    const float* __restrict__ pooled,
    const float* __restrict__ deg,
    const float* __restrict__ w1,
    const float* __restrict__ b1,
    const float* __restrict__ w2,
    const float* __restrict__ b2,
    float*       __restrict__ out)
{
    const int g = blockIdx.x * 64 + threadIdx.x;
    if (g >= NG) return;
    float cnt = deg[g];
    cnt = cnt > 1.0f ? cnt : 1.0f;

    float p[HD];
    #pragma unroll
    for (int i = 0; i < HD; ++i) p[i] = pooled[g * HD + i] / cnt;

    float hid[HD];
    #pragma unroll
    for (int j = 0; j < HD; ++j) {
        float a = b1[j];
        #pragma unroll
        for (int i = 0; i < HD; ++i)
            a = fmaf(p[i], w1[i * HD + j], a);
        hid[j] = a > 0.0f ? a : 0.0f;
    }
    #pragma unroll
    for (int t = 0; t < TOUT; ++t) {
        float a = b2[t];
        #pragma unroll
        for (int j = 0; j < HD; ++j)
            a = fmaf(hid[j], w2[j * TOUT + t], a);
        out[g * TOUT + t] = a;
    }
}

// ---------------------------------------------------------------------------
extern "C" void kernel_launch(void* const* d_in, const int* in_sizes, int n_in,
                              void* d_out, int out_size, void* d_ws, size_t ws_size,
                              hipStream_t stream)
{
    const float* x        = (const float*)d_in[0];
    const float* ea       = (const float*)d_in[1];
    const int*   eidx     = (const int*)  d_in[2];
    const int*   batch    = (const int*)  d_in[3];
    const float* c1_nn_w  = (const float*)d_in[4];
    const float* c1_nn_b  = (const float*)d_in[5];
    const float* c1_root  = (const float*)d_in[6];
    const float* c1_bias  = (const float*)d_in[7];
    const float* c2_nn_w  = (const float*)d_in[8];
    const float* c2_nn_b  = (const float*)d_in[9];
    const float* c2_root  = (const float*)d_in[10];
    const float* c2_bias  = (const float*)d_in[11];
    const float* c3_nn_w  = (const float*)d_in[12];
    const float* c3_nn_b  = (const float*)d_in[13];
    const float* c3_root  = (const float*)d_in[14];
    const float* c3_bias  = (const float*)d_in[15];
    const float* bn1_g    = (const float*)d_in[16];
    const float* bn1_b    = (const float*)d_in[17];
    const float* bn1_m    = (const float*)d_in[18];
    const float* bn1_v    = (const float*)d_in[19];
    const float* bn2_g    = (const float*)d_in[20];
    const float* bn2_b    = (const float*)d_in[21];
    const float* bn2_m    = (const float*)d_in[22];
    const float* bn2_v    = (const float*)d_in[23];
    const float* mlp_w1   = (const float*)d_in[24];
    const float* mlp_b1   = (const float*)d_in[25];
    const float* mlp_w2   = (const float*)d_in[26];
    const float* mlp_b2   = (const float*)d_in[27];
    float* out = (float*)d_out;

    // workspace layout (deg_g and pooled adjacent -> single memset)
    float* h1     = (float*)d_ws;            // NN*32
    float* h2     = h1 + NN * HD;            // NN*32
    float* deg_g  = h2 + NN * HD;            // NG
    float* pooled = deg_g + NG;              // NG*32
    int*   ibase  = (int*)(pooled + NG * HD);
    int2*  csr    = (int2*)ibase;            // NE int2
    int*   deg_in = ibase + 2 * NE;          // NN
    int*   row_s  = deg_in + NN;             // NN+1
    int*   cursor = row_s + NN + 1;          // NN
    int*   bsum   = cursor + NN;             // NB_SCAN
    int*   boff   = bsum + NB_SCAN;          // NB_SCAN

    hipMemsetAsync(deg_in, 0, sizeof(int) * NN, stream);
    hipMemsetAsync(deg_g,  0, sizeof(float) * (NG + NG * HD), stream);

    const int egrid = (NE + 255) / 256;

    count_deg_kernel<<<egrid, 256, 0, stream>>>(eidx, batch, deg_in, deg_g);
    scan_phase1<<<NB_SCAN, 1024, 0, stream>>>(deg_in, row_s, bsum);
    scan_phase2<<<1, 64, 0, stream>>>(bsum, boff);
    scan_phase3<<<NB_SCAN, 1024, 0, stream>>>(boff, row_s, cursor);
    csr_scatter<<<egrid, 256, 0, stream>>>(eidx, cursor, csr);

    const int lgrid = NN / 16;  // 1875, 16 nodes per block

    fused_layer<FIN, false><<<lgrid, 256, 0, stream>>>(
        x, ea, csr, row_s, c1_nn_w, c1_nn_b, c1_root, c1_bias,
        batch, deg_g, bn1_g, bn1_b, bn1_m, bn1_v, h1);

    fused_layer<HD, false><<<lgrid, 256, 0, stream>>>(
        h1, ea, csr, row_s, c2_nn_w, c2_nn_b, c2_root, c2_bias,
        batch, deg_g, bn2_g, bn2_b, bn2_m, bn2_v, h2);

    fused_layer<HD, true><<<lgrid, 256, 0, stream>>>(
        h2, ea, csr, row_s, c3_nn_w, c3_nn_b, c3_root, c3_bias,
        batch, deg_g, nullptr, nullptr, nullptr, nullptr, pooled);

    head_kernel<<<(NG + 63) / 64, 64, 0, stream>>>(pooled, deg_g, mlp_w1, mlp_b1,
                                                   mlp_w2, mlp_b2, out);
}